// Round 5
// baseline (127.461 us; speedup 1.0000x reference)
//
#include <hip/hip_runtime.h>
#include <hip/hip_bf16.h>
#include <math.h>

#define D_MODEL 1024
#define C_DIM   128
#define BATCH   4
#define SEQ     2048
#define BS_ROWS (BATCH*SEQ)

typedef float  f32x4 __attribute__((ext_vector_type(4)));
typedef short  s16x8 __attribute__((ext_vector_type(8)));
typedef unsigned short u16;
typedef unsigned short u16x4 __attribute__((ext_vector_type(4)));
typedef unsigned short u16x8 __attribute__((ext_vector_type(8)));

__device__ inline u16 f2bf(float f){
    unsigned u = __builtin_bit_cast(unsigned, f);
    u += 0x7FFF + ((u >> 16) & 1);          // round-to-nearest-even
    return (u16)(u >> 16);
}
__device__ inline float bf2f(u16 h){
    unsigned u = ((unsigned)h) << 16;
    return __builtin_bit_cast(float, u);
}

// async global->LDS, 16B per lane; LDS dest = wave-uniform base + lane*16
__device__ inline void gl_lds16(const u16* g, u16* l){
    __builtin_amdgcn_global_load_lds(
        (const __attribute__((address_space(1))) void*)g,
        (__attribute__((address_space(3))) void*)l,
        16, 0, 0);
}

// ---------------------------------------------------------------------------
// bf16 MFMA GEMM:  C[M,N] = scale * A[M,K] @ BT[N,K]^T
// BMxBN tile, BK=64, 4 waves in 2x2 grid, per-wave (BM/2)x(BN/2) via
// FM x FN frags of 16x16x32 MFMA. m97 structure: single-buffer LDS,
// stage -> vmcnt(0)+barrier -> compute -> barrier; TLP provides pipelining.
// OUT_BF16: bf16 output. MASK: fp32 mask multiply in epilogue (q path only).
// CSKIP: skip tiles fully above causal diagonal. CK: causal K-extent.
// QKF: fused q/k projection — blockIdx.y = path*(128/BN)+nt.
// ---------------------------------------------------------------------------
template<int BM, int BN, int OUT_BF16, int MASK, int CSKIP, int CK, int QKF>
__launch_bounds__(256)
__global__ void gemm_bt(const u16* __restrict__ Ag, const u16* __restrict__ Bg,
                        const u16* __restrict__ Bg2,
                        void* __restrict__ Cg, void* __restrict__ Cg2,
                        const float* __restrict__ maskp,
                        int K, int lda, int ldb, int ldc,
                        long sA, long sB, long sC, float scale)
{
    constexpr int FM = BM / 32, FN = BN / 32;
    __shared__ u16 As[BM * 64];
    __shared__ u16 Bs[BN * 64];
    const int mt = blockIdx.x;
    int nt, path = 0;
    if (QKF) { constexpr int NT = C_DIM / BN; path = blockIdx.y / NT; nt = blockIdx.y % NT; }
    else nt = blockIdx.y;
    if (CSKIP && nt * BN >= (mt + 1) * BM) return;   // fully above diagonal
    const u16* Aa = Ag + (long)blockIdx.z * sA;
    const u16* Bb = ((QKF && path) ? Bg2 : Bg) + (long)blockIdx.z * sB;
    const int tid = threadIdx.x, lane = tid & 63, wave = tid >> 6;
    const int wr = wave >> 1, wc = wave & 1;
    const int mbase = mt * BM, nbase = nt * BN;
    int Keff = K;
    if (CK) { int ke = (mt + 1) * BM; Keff = ke < K ? ke : K; }
    const int nkt = Keff >> 6;

    f32x4 acc[FM][FN];
    #pragma unroll
    for (int m = 0; m < FM; ++m)
        #pragma unroll
        for (int n = 0; n < FN; ++n) acc[m][n] = (f32x4){0.f,0.f,0.f,0.f};

    // staging lane geometry: each wave stages 8 rows x 128B per shot;
    // lane covers 16B at XOR-swizzled col slot
    const int sr  = lane >> 3;                 // row within wave-chunk (0..7)
    const int sc8 = (lane & 7) ^ sr;           // swizzled 8-elem col slot

    for (int kt = 0; kt < nkt; ++kt) {
        const int k0 = kt * 64;
        #pragma unroll
        for (int s = 0; s < BM / 32; ++s) {
            const int row = s * 32 + wave * 8 + sr;
            gl_lds16(Aa + (size_t)(mbase + row) * lda + k0 + sc8 * 8,
                     &As[s * 2048 + wave * 512]);
        }
        #pragma unroll
        for (int s = 0; s < BN / 32; ++s) {
            const int row = s * 32 + wave * 8 + sr;
            gl_lds16(Bb + (size_t)(nbase + row) * ldb + k0 + sc8 * 8,
                     &Bs[s * 2048 + wave * 512]);
        }
        asm volatile("s_waitcnt vmcnt(0)" ::: "memory");
        __syncthreads();

        #pragma unroll
        for (int ks = 0; ks < 2; ++ks) {
            s16x8 af[FM], bfr[FN];
            const int k8 = ks * 4 + (lane >> 4);
            #pragma unroll
            for (int m = 0; m < FM; ++m) {
                const int row = wr * (BM / 2) + m * 16 + (lane & 15);
                af[m] = *(const s16x8*)&As[row * 64 + ((k8 ^ (row & 7)) << 3)];
            }
            #pragma unroll
            for (int n = 0; n < FN; ++n) {
                const int row = wc * (BN / 2) + n * 16 + (lane & 15);
                bfr[n] = *(const s16x8*)&Bs[row * 64 + ((k8 ^ (row & 7)) << 3)];
            }
            #pragma unroll
            for (int m = 0; m < FM; ++m)
                #pragma unroll
                for (int n = 0; n < FN; ++n)
                    acc[m][n] = __builtin_amdgcn_mfma_f32_16x16x32_bf16(af[m], bfr[n], acc[m][n], 0, 0, 0);
        }
        __syncthreads();
    }

    // epilogue: C/D layout col=lane&15, row=(lane>>4)*4+r (m89-verified)
    const bool kpath = QKF && path;
    void* Cout = kpath ? Cg2 : Cg;
    const int lr = (lane >> 4) * 4, lc = lane & 15;
    #pragma unroll
    for (int m = 0; m < FM; ++m) {
        #pragma unroll
        for (int n = 0; n < FN; ++n) {
            const int gr = mbase + wr * (BM / 2) + m * 16 + lr;
            const int gc = nbase + wc * (BN / 2) + n * 16 + lc;
            #pragma unroll
            for (int r = 0; r < 4; ++r) {
                float f = acc[m][n][r] * scale;
                const size_t off = (size_t)(gr + r) * ldc + gc;
                if (MASK) { if (!kpath) f *= maskp[(long)blockIdx.z * sC + off]; }
                if (OUT_BF16) ((u16*)Cout + (long)blockIdx.z * sC)[off] = f2bf(f);
                else          ((float*)Cout + (long)blockIdx.z * sC)[off] = f;
            }
        }
    }
}

// ---------------------------------------------------------------------------
// Row softmax over causal prefix, in place on bf16 scores (vectorized).
// Masked lanes fold to exp->0, which also zero-fills (q, 128-boundary).
// ---------------------------------------------------------------------------
__launch_bounds__(256)
__global__ void softmax_rows(u16* __restrict__ sc)
{
    __shared__ float v[SEQ];
    __shared__ float red[8];
    const int bq = blockIdx.x;
    const int q  = bq & (SEQ - 1);
    u16* row = sc + (size_t)bq * SEQ;
    const int tid = threadIdx.x;
    const int nk = q + 1;
    const int bound = ((q >> 7) + 1) << 7;   // next multiple of 128
    const int nv = bound >> 3;               // u16x8 chunks

    float lmax = -1e30f;
    for (int ci = tid; ci < nv; ci += 256) {
        const int base = ci * 8;
        u16x8 vv = *(const u16x8*)&row[base];
        #pragma unroll
        for (int j = 0; j < 8; ++j) {
            float f = (base + j < nk) ? bf2f(vv[j]) : -1e30f;
            v[base + j] = f;
            lmax = fmaxf(lmax, f);
        }
    }
    for (int off = 32; off; off >>= 1) lmax = fmaxf(lmax, __shfl_xor(lmax, off));
    if ((tid & 63) == 0) red[tid >> 6] = lmax;
    __syncthreads();
    const float m = fmaxf(fmaxf(red[0], red[1]), fmaxf(red[2], red[3]));

    float ls = 0.f;
    for (int ci = tid; ci < nv; ci += 256) {
        const int base = ci * 8;
        #pragma unroll
        for (int j = 0; j < 8; ++j) {
            float e = __expf(v[base + j] - m);   // masked: exp(-1e30-m)=0
            v[base + j] = e;
            ls += e;
        }
    }
    for (int off = 32; off; off >>= 1) ls += __shfl_xor(ls, off);
    if ((tid & 63) == 0) red[4 + (tid >> 6)] = ls;
    __syncthreads();
    const float inv = 1.f / (red[4] + red[5] + red[6] + red[7]);

    for (int ci = tid; ci < nv; ci += 256) {
        const int base = ci * 8;
        u16x8 o;
        #pragma unroll
        for (int j = 0; j < 8; ++j) o[j] = f2bf(v[base + j] * inv);
        *(u16x8*)&row[base] = o;
    }
}

// ---------------------------------------------------------------------------
// x prep: read x once; write xb (bf16 row-major) and xbT (bf16 [b][D][S])
// ---------------------------------------------------------------------------
__launch_bounds__(256)
__global__ void xprep(const float* __restrict__ x, u16* __restrict__ xb,
                      u16* __restrict__ xbT)
{
    __shared__ float t[32][33];
    const int b = blockIdx.z;
    const float* xp = x + (long)b * SEQ * D_MODEL;
    const int c0 = blockIdx.x * 32, r0 = blockIdx.y * 32;
    const int tx = threadIdx.x & 31, ty = threadIdx.x >> 5;   // ty 0..7
    #pragma unroll
    for (int i = 0; i < 32; i += 8) {
        const float f = xp[(size_t)(r0 + ty + i) * D_MODEL + c0 + tx];
        t[ty + i][tx] = f;
        xb[((long)b * SEQ + r0 + ty + i) * D_MODEL + c0 + tx] = f2bf(f);
    }
    __syncthreads();
    #pragma unroll
    for (int i = 0; i < 32; i += 8)
        xbT[((long)b * D_MODEL + c0 + ty + i) * SEQ + r0 + tx] = f2bf(t[tx][ty + i]);
}

// ---------------------------------------------------------------------------
// fp32 -> bf16 transpose (32x32 LDS tiles): out[c][r] = in[r][c]
// ---------------------------------------------------------------------------
__launch_bounds__(256)
__global__ void transpose_cvt(const float* __restrict__ in, u16* __restrict__ out,
                              int R, int Cc)
{
    __shared__ float t[32][33];
    const int c0 = blockIdx.x * 32, r0 = blockIdx.y * 32;
    const int tx = threadIdx.x & 31, ty = threadIdx.x >> 5;
    #pragma unroll
    for (int i = 0; i < 32; i += 8) t[ty + i][tx] = in[(size_t)(r0 + ty + i) * Cc + c0 + tx];
    __syncthreads();
    #pragma unroll
    for (int i = 0; i < 32; i += 8) out[(size_t)(c0 + ty + i) * R + r0 + tx] = f2bf(t[tx][ty + i]);
}

// fp32 -> bf16 straight convert (vectorized), n4 = n/4
__launch_bounds__(256)
__global__ void convert_cvt(const float* __restrict__ in, u16* __restrict__ out, int n4)
{
    for (int i = blockIdx.x * 256 + threadIdx.x; i < n4; i += gridDim.x * 256) {
        float4 f = reinterpret_cast<const float4*>(in)[i];
        u16x4 o = { f2bf(f.x), f2bf(f.y), f2bf(f.z), f2bf(f.w) };
        reinterpret_cast<u16x4*>(out)[i] = o;
    }
}

// ---------------------------------------------------------------------------
extern "C" void kernel_launch(void* const* d_in, const int* in_sizes, int n_in,
                              void* d_out, int out_size, void* d_ws, size_t ws_size,
                              hipStream_t stream)
{
    const float* x    = (const float*)d_in[0];
    const float* A    = (const float*)d_in[1];
    const float* Bm   = (const float*)d_in[2];
    const float* ov   = (const float*)d_in[3];
    const float* mask = (const float*)d_in[4];

    // workspace layout (bf16): total ~86.5 MiB
    char* w = (char*)d_ws;
    u16* xb  = (u16*)w; w += (size_t)BS_ROWS * D_MODEL * 2;   // x row-major
    u16* xbT = (u16*)w; w += (size_t)BS_ROWS * D_MODEL * 2;   // x^T per batch [D][S]
    u16* AbT = (u16*)w; w += (size_t)C_DIM * D_MODEL * 2;     // A^T [C][D]
    u16* Bmb = (u16*)w; w += (size_t)C_DIM * D_MODEL * 2;     // Bmat [C][D]
    u16* ovT = (u16*)w; w += (size_t)D_MODEL * D_MODEL * 2;   // ov^T [D][D]
    u16* qm  = (u16*)w; w += (size_t)BS_ROWS * C_DIM * 2;     // masked q
    u16* kk  = (u16*)w; w += (size_t)BS_ROWS * C_DIM * 2;     // k
    u16* sc  = (u16*)w; w += (size_t)BATCH * SEQ * SEQ * 2;   // scores -> P (in place)
    u16* zb  = (u16*)w; w += (size_t)BS_ROWS * D_MODEL * 2;   // z

    // prep: x (read once -> xb + xbT), Bmat convert, ov/A transposes
    xprep<<<dim3(D_MODEL/32, SEQ/32, BATCH), 256, 0, stream>>>(x, xb, xbT);
    convert_cvt<<<128, 256, 0, stream>>>(Bm, Bmb, C_DIM * D_MODEL / 4);
    transpose_cvt<<<dim3(D_MODEL/32, D_MODEL/32, 1), 256, 0, stream>>>(ov, ovT, D_MODEL, D_MODEL);
    transpose_cvt<<<dim3(C_DIM/32, D_MODEL/32, 1), 256, 0, stream>>>(A, AbT, D_MODEL, C_DIM);

    // fused q & k projection: 64x64 tiles, y = path*2 + nt -> 512 blocks
    gemm_bt<64,64,1,1,0,0,1><<<dim3(BS_ROWS/64, 4, 1), 256, 0, stream>>>(
        xb, AbT, Bmb, qm, kk, mask,
        D_MODEL, D_MODEL, D_MODEL, C_DIM, 0, 0, 0, 1.0f);

    // scores = qm @ kk^T / D  (128x128 tiles, causal lower tiles only)
    gemm_bt<128,128,1,0,1,0,0><<<dim3(SEQ/128, SEQ/128, BATCH), 256, 0, stream>>>(
        qm, kk, nullptr, sc, nullptr, nullptr, C_DIM, C_DIM, C_DIM, SEQ,
        (long)SEQ * C_DIM, (long)SEQ * C_DIM, (long)SEQ * SEQ, 1.0f / D_MODEL);

    softmax_rows<<<BS_ROWS, 256, 0, stream>>>(sc);

    // z = P @ x  (128x128 tiles, causal K-extent) -> 512 blocks
    gemm_bt<128,128,1,0,0,1,0><<<dim3(SEQ/128, D_MODEL/128, BATCH), 256, 0, stream>>>(
        sc, xbT, nullptr, zb, nullptr, nullptr, SEQ, SEQ, SEQ, D_MODEL,
        (long)SEQ * SEQ, (long)D_MODEL * SEQ, (long)SEQ * D_MODEL, 1.0f);

    // out = z @ ov  (128x128 tiles) -> 512 blocks, fp32 out
    gemm_bt<128,128,0,0,0,0,0><<<dim3(BS_ROWS/128, D_MODEL/128, 1), 256, 0, stream>>>(
        zb, ovT, nullptr, d_out, nullptr, nullptr, D_MODEL, D_MODEL, D_MODEL, D_MODEL,
        0, 0, 0, 1.0f);
}

// Round 6
// 123.540 us; speedup vs baseline: 1.0317x; 1.0317x over previous
//
#include <hip/hip_runtime.h>
#include <hip/hip_bf16.h>
#include <math.h>

#define D_MODEL 1024
#define C_DIM   128
#define BATCH   4
#define SEQ     2048
#define BS_ROWS (BATCH*SEQ)

typedef float  f32x4 __attribute__((ext_vector_type(4)));
typedef short  s16x8 __attribute__((ext_vector_type(8)));
typedef unsigned short u16;
typedef unsigned short u16x4 __attribute__((ext_vector_type(4)));
typedef unsigned short u16x8 __attribute__((ext_vector_type(8)));

__device__ inline u16 f2bf(float f){
    unsigned u = __builtin_bit_cast(unsigned, f);
    u += 0x7FFF + ((u >> 16) & 1);          // round-to-nearest-even
    return (u16)(u >> 16);
}
__device__ inline float bf2f(u16 h){
    unsigned u = ((unsigned)h) << 16;
    return __builtin_bit_cast(float, u);
}

// async global->LDS, 16B per lane; LDS dest = wave-uniform base + lane*16
__device__ inline void gl_lds16(const u16* g, u16* l){
    __builtin_amdgcn_global_load_lds(
        (const __attribute__((address_space(1))) void*)g,
        (__attribute__((address_space(3))) void*)l,
        16, 0, 0);
}

// counted vmem wait (T4): wait until <= N vmem ops outstanding (per wave)
template<int N> __device__ inline void wait_vm(){
    if constexpr (N <= 0)      asm volatile("s_waitcnt vmcnt(0)" ::: "memory");
    else if constexpr (N == 2) asm volatile("s_waitcnt vmcnt(2)" ::: "memory");
    else if constexpr (N == 4) asm volatile("s_waitcnt vmcnt(4)" ::: "memory");
    else if constexpr (N == 6) asm volatile("s_waitcnt vmcnt(6)" ::: "memory");
    else if constexpr (N == 8) asm volatile("s_waitcnt vmcnt(8)" ::: "memory");
    else                       asm volatile("s_waitcnt vmcnt(0)" ::: "memory");
}

// ---------------------------------------------------------------------------
// bf16 MFMA GEMM:  C[M,N] = scale * A[M,K] @ BT[N,K]^T
// BMxBN tile, BK=64, 4 waves in 2x2 grid, per-wave (BM/2)x(BN/2) via
// FM x FN frags of 16x16x32 MFMA.
// Pipeline (T3/T4-lite): double-buffered LDS; per K-step issue next tile's
// global_load_lds, then s_waitcnt vmcnt(NL) — waits ONLY the current tile's
// loads; the prefetch stays in flight across compute.
// OUT_BF16: bf16 output. MASK: fp32 mask multiply in epilogue (q path only).
// CSKIP: skip tiles fully above causal diagonal. CK: causal K-extent.
// QKF: fused q/k projection — blockIdx.y = path*(128/BN)+nt.
// ---------------------------------------------------------------------------
template<int BM, int BN, int OUT_BF16, int MASK, int CSKIP, int CK, int QKF>
__launch_bounds__(256)
__global__ void gemm_bt(const u16* __restrict__ Ag, const u16* __restrict__ Bg,
                        const u16* __restrict__ Bg2,
                        void* __restrict__ Cg, void* __restrict__ Cg2,
                        const float* __restrict__ maskp,
                        int K, int lda, int ldb, int ldc,
                        long sA, long sB, long sC, float scale)
{
    constexpr int FM = BM / 32, FN = BN / 32;
    constexpr int NL = BM / 32 + BN / 32;   // gl_lds issues per wave per tile
    __shared__ u16 As[2][BM * 64];
    __shared__ u16 Bs[2][BN * 64];
    const int mt = blockIdx.x;
    int nt, path = 0;
    if (QKF) { constexpr int NT = C_DIM / BN; path = blockIdx.y / NT; nt = blockIdx.y % NT; }
    else nt = blockIdx.y;
    if (CSKIP && nt * BN >= (mt + 1) * BM) return;   // fully above diagonal
    const u16* Aa = Ag + (long)blockIdx.z * sA;
    const u16* Bb = ((QKF && path) ? Bg2 : Bg) + (long)blockIdx.z * sB;
    const int tid = threadIdx.x, lane = tid & 63, wave = tid >> 6;
    const int wr = wave >> 1, wc = wave & 1;
    const int mbase = mt * BM, nbase = nt * BN;
    int Keff = K;
    if (CK) { int ke = (mt + 1) * BM; Keff = ke < K ? ke : K; }
    const int nkt = Keff >> 6;

    f32x4 acc[FM][FN];
    #pragma unroll
    for (int m = 0; m < FM; ++m)
        #pragma unroll
        for (int n = 0; n < FN; ++n) acc[m][n] = (f32x4){0.f,0.f,0.f,0.f};

    // staging lane geometry: each wave stages 8 rows x 128B per shot;
    // lane covers 16B at XOR-swizzled col slot
    const int sr  = lane >> 3;                 // row within wave-chunk (0..7)
    const int sc8 = (lane & 7) ^ sr;           // swizzled 8-elem col slot

    auto STAGE = [&](int buf, int kt) {
        const int k0 = kt * 64;
        #pragma unroll
        for (int s = 0; s < BM / 32; ++s) {
            const int row = s * 32 + wave * 8 + sr;
            gl_lds16(Aa + (size_t)(mbase + row) * lda + k0 + sc8 * 8,
                     &As[buf][s * 2048 + wave * 512]);
        }
        #pragma unroll
        for (int s = 0; s < BN / 32; ++s) {
            const int row = s * 32 + wave * 8 + sr;
            gl_lds16(Bb + (size_t)(nbase + row) * ldb + k0 + sc8 * 8,
                     &Bs[buf][s * 2048 + wave * 512]);
        }
    };

    STAGE(0, 0);
    int cur = 0;
    for (int kt = 0; kt < nkt; ++kt) {
        if (kt + 1 < nkt) {
            STAGE(cur ^ 1, kt + 1);   // prefetch next tile (NL more in flight)
            wait_vm<NL>();            // retire ONLY current tile's loads
        } else {
            wait_vm<0>();
        }
        __syncthreads();

        const u16* Ap = As[cur];
        const u16* Bp = Bs[cur];
        #pragma unroll
        for (int ks = 0; ks < 2; ++ks) {
            s16x8 af[FM], bfr[FN];
            const int k8 = ks * 4 + (lane >> 4);
            #pragma unroll
            for (int m = 0; m < FM; ++m) {
                const int row = wr * (BM / 2) + m * 16 + (lane & 15);
                af[m] = *(const s16x8*)&Ap[row * 64 + ((k8 ^ (row & 7)) << 3)];
            }
            #pragma unroll
            for (int n = 0; n < FN; ++n) {
                const int row = wc * (BN / 2) + n * 16 + (lane & 15);
                bfr[n] = *(const s16x8*)&Bp[row * 64 + ((k8 ^ (row & 7)) << 3)];
            }
            #pragma unroll
            for (int m = 0; m < FM; ++m)
                #pragma unroll
                for (int n = 0; n < FN; ++n)
                    acc[m][n] = __builtin_amdgcn_mfma_f32_16x16x32_bf16(af[m], bfr[n], acc[m][n], 0, 0, 0);
        }
        __syncthreads();   // all waves done reading buf cur before it is re-staged
        cur ^= 1;
    }

    // epilogue: C/D layout col=lane&15, row=(lane>>4)*4+r (m89-verified)
    const bool kpath = QKF && path;
    void* Cout = kpath ? Cg2 : Cg;
    const int lr = (lane >> 4) * 4, lc = lane & 15;
    #pragma unroll
    for (int m = 0; m < FM; ++m) {
        #pragma unroll
        for (int n = 0; n < FN; ++n) {
            const int gr = mbase + wr * (BM / 2) + m * 16 + lr;
            const int gc = nbase + wc * (BN / 2) + n * 16 + lc;
            #pragma unroll
            for (int r = 0; r < 4; ++r) {
                float f = acc[m][n][r] * scale;
                const size_t off = (size_t)(gr + r) * ldc + gc;
                if (MASK) { if (!kpath) f *= maskp[(long)blockIdx.z * sC + off]; }
                if (OUT_BF16) ((u16*)Cout + (long)blockIdx.z * sC)[off] = f2bf(f);
                else          ((float*)Cout + (long)blockIdx.z * sC)[off] = f;
            }
        }
    }
}

// ---------------------------------------------------------------------------
// Row softmax over causal prefix, in place on bf16 scores (vectorized).
// Masked lanes fold to exp->0, which also zero-fills (q, 128-boundary).
// ---------------------------------------------------------------------------
__launch_bounds__(256)
__global__ void softmax_rows(u16* __restrict__ sc)
{
    __shared__ float v[SEQ];
    __shared__ float red[8];
    const int bq = blockIdx.x;
    const int q  = bq & (SEQ - 1);
    u16* row = sc + (size_t)bq * SEQ;
    const int tid = threadIdx.x;
    const int nk = q + 1;
    const int bound = ((q >> 7) + 1) << 7;   // next multiple of 128
    const int nv = bound >> 3;               // u16x8 chunks

    float lmax = -1e30f;
    for (int ci = tid; ci < nv; ci += 256) {
        const int base = ci * 8;
        u16x8 vv = *(const u16x8*)&row[base];
        #pragma unroll
        for (int j = 0; j < 8; ++j) {
            float f = (base + j < nk) ? bf2f(vv[j]) : -1e30f;
            v[base + j] = f;
            lmax = fmaxf(lmax, f);
        }
    }
    for (int off = 32; off; off >>= 1) lmax = fmaxf(lmax, __shfl_xor(lmax, off));
    if ((tid & 63) == 0) red[tid >> 6] = lmax;
    __syncthreads();
    const float m = fmaxf(fmaxf(red[0], red[1]), fmaxf(red[2], red[3]));

    float ls = 0.f;
    for (int ci = tid; ci < nv; ci += 256) {
        const int base = ci * 8;
        #pragma unroll
        for (int j = 0; j < 8; ++j) {
            float e = __expf(v[base + j] - m);   // masked: exp(-1e30-m)=0
            v[base + j] = e;
            ls += e;
        }
    }
    for (int off = 32; off; off >>= 1) ls += __shfl_xor(ls, off);
    if ((tid & 63) == 0) red[4 + (tid >> 6)] = ls;
    __syncthreads();
    const float inv = 1.f / (red[4] + red[5] + red[6] + red[7]);

    for (int ci = tid; ci < nv; ci += 256) {
        const int base = ci * 8;
        u16x8 o;
        #pragma unroll
        for (int j = 0; j < 8; ++j) o[j] = f2bf(v[base + j] * inv);
        *(u16x8*)&row[base] = o;
    }
}

// ---------------------------------------------------------------------------
// x prep: read x once; write xb (bf16 row-major) and xbT (bf16 [b][D][S])
// ---------------------------------------------------------------------------
__launch_bounds__(256)
__global__ void xprep(const float* __restrict__ x, u16* __restrict__ xb,
                      u16* __restrict__ xbT)
{
    __shared__ float t[32][33];
    const int b = blockIdx.z;
    const float* xp = x + (long)b * SEQ * D_MODEL;
    const int c0 = blockIdx.x * 32, r0 = blockIdx.y * 32;
    const int tx = threadIdx.x & 31, ty = threadIdx.x >> 5;   // ty 0..7
    #pragma unroll
    for (int i = 0; i < 32; i += 8) {
        const float f = xp[(size_t)(r0 + ty + i) * D_MODEL + c0 + tx];
        t[ty + i][tx] = f;
        xb[((long)b * SEQ + r0 + ty + i) * D_MODEL + c0 + tx] = f2bf(f);
    }
    __syncthreads();
    #pragma unroll
    for (int i = 0; i < 32; i += 8)
        xbT[((long)b * D_MODEL + c0 + ty + i) * SEQ + r0 + tx] = f2bf(t[tx][ty + i]);
}

// ---------------------------------------------------------------------------
// fp32 -> bf16 transpose (32x32 LDS tiles): out[c][r] = in[r][c]
// ---------------------------------------------------------------------------
__launch_bounds__(256)
__global__ void transpose_cvt(const float* __restrict__ in, u16* __restrict__ out,
                              int R, int Cc)
{
    __shared__ float t[32][33];
    const int c0 = blockIdx.x * 32, r0 = blockIdx.y * 32;
    const int tx = threadIdx.x & 31, ty = threadIdx.x >> 5;
    #pragma unroll
    for (int i = 0; i < 32; i += 8) t[ty + i][tx] = in[(size_t)(r0 + ty + i) * Cc + c0 + tx];
    __syncthreads();
    #pragma unroll
    for (int i = 0; i < 32; i += 8) out[(size_t)(c0 + ty + i) * R + r0 + tx] = f2bf(t[tx][ty + i]);
}

// fp32 -> bf16 straight convert (vectorized), n4 = n/4
__launch_bounds__(256)
__global__ void convert_cvt(const float* __restrict__ in, u16* __restrict__ out, int n4)
{
    for (int i = blockIdx.x * 256 + threadIdx.x; i < n4; i += gridDim.x * 256) {
        float4 f = reinterpret_cast<const float4*>(in)[i];
        u16x4 o = { f2bf(f.x), f2bf(f.y), f2bf(f.z), f2bf(f.w) };
        reinterpret_cast<u16x4*>(out)[i] = o;
    }
}

// ---------------------------------------------------------------------------
extern "C" void kernel_launch(void* const* d_in, const int* in_sizes, int n_in,
                              void* d_out, int out_size, void* d_ws, size_t ws_size,
                              hipStream_t stream)
{
    const float* x    = (const float*)d_in[0];
    const float* A    = (const float*)d_in[1];
    const float* Bm   = (const float*)d_in[2];
    const float* ov   = (const float*)d_in[3];
    const float* mask = (const float*)d_in[4];

    // workspace layout (bf16): total ~86.5 MiB
    char* w = (char*)d_ws;
    u16* xb  = (u16*)w; w += (size_t)BS_ROWS * D_MODEL * 2;   // x row-major
    u16* xbT = (u16*)w; w += (size_t)BS_ROWS * D_MODEL * 2;   // x^T per batch [D][S]
    u16* AbT = (u16*)w; w += (size_t)C_DIM * D_MODEL * 2;     // A^T [C][D]
    u16* Bmb = (u16*)w; w += (size_t)C_DIM * D_MODEL * 2;     // Bmat [C][D]
    u16* ovT = (u16*)w; w += (size_t)D_MODEL * D_MODEL * 2;   // ov^T [D][D]
    u16* qm  = (u16*)w; w += (size_t)BS_ROWS * C_DIM * 2;     // masked q
    u16* kk  = (u16*)w; w += (size_t)BS_ROWS * C_DIM * 2;     // k
    u16* sc  = (u16*)w; w += (size_t)BATCH * SEQ * SEQ * 2;   // scores -> P (in place)
    u16* zb  = (u16*)w; w += (size_t)BS_ROWS * D_MODEL * 2;   // z

    // prep: x (read once -> xb + xbT), Bmat convert, ov/A transposes
    xprep<<<dim3(D_MODEL/32, SEQ/32, BATCH), 256, 0, stream>>>(x, xb, xbT);
    convert_cvt<<<128, 256, 0, stream>>>(Bm, Bmb, C_DIM * D_MODEL / 4);
    transpose_cvt<<<dim3(D_MODEL/32, D_MODEL/32, 1), 256, 0, stream>>>(ov, ovT, D_MODEL, D_MODEL);
    transpose_cvt<<<dim3(C_DIM/32, D_MODEL/32, 1), 256, 0, stream>>>(A, AbT, D_MODEL, C_DIM);

    // fused q & k projection: 64x64 tiles, y = path*2 + nt -> 512 blocks
    gemm_bt<64,64,1,1,0,0,1><<<dim3(BS_ROWS/64, 4, 1), 256, 0, stream>>>(
        xb, AbT, Bmb, qm, kk, mask,
        D_MODEL, D_MODEL, D_MODEL, C_DIM, 0, 0, 0, 1.0f);

    // scores = qm @ kk^T / D  (128x128 tiles, causal lower tiles only)
    gemm_bt<128,128,1,0,1,0,0><<<dim3(SEQ/128, SEQ/128, BATCH), 256, 0, stream>>>(
        qm, kk, nullptr, sc, nullptr, nullptr, C_DIM, C_DIM, C_DIM, SEQ,
        (long)SEQ * C_DIM, (long)SEQ * C_DIM, (long)SEQ * SEQ, 1.0f / D_MODEL);

    softmax_rows<<<BS_ROWS, 256, 0, stream>>>(sc);

    // z = P @ x  (128x128 tiles, causal K-extent) -> 512 blocks
    gemm_bt<128,128,1,0,0,1,0><<<dim3(SEQ/128, D_MODEL/128, BATCH), 256, 0, stream>>>(
        sc, xbT, nullptr, zb, nullptr, nullptr, SEQ, SEQ, SEQ, D_MODEL,
        (long)SEQ * SEQ, (long)D_MODEL * SEQ, (long)SEQ * D_MODEL, 1.0f);

    // out = z @ ov  (128x128 tiles) -> 512 blocks, fp32 out
    gemm_bt<128,128,0,0,0,0,0><<<dim3(BS_ROWS/128, D_MODEL/128, 1), 256, 0, stream>>>(
        zb, ovT, nullptr, d_out, nullptr, nullptr, D_MODEL, D_MODEL, D_MODEL, D_MODEL,
        0, 0, 0, 1.0f);
}

// Round 7
// 122.686 us; speedup vs baseline: 1.0389x; 1.0070x over previous
//
#include <hip/hip_runtime.h>
#include <hip/hip_bf16.h>
#include <math.h>

#define D_MODEL 1024
#define C_DIM   128
#define BATCH   4
#define SEQ     2048
#define BS_ROWS (BATCH*SEQ)

typedef float  f32x4 __attribute__((ext_vector_type(4)));
typedef short  s16x8 __attribute__((ext_vector_type(8)));
typedef unsigned short u16;
typedef unsigned short u16x4 __attribute__((ext_vector_type(4)));
typedef unsigned short u16x8 __attribute__((ext_vector_type(8)));

__device__ inline u16 f2bf(float f){
    unsigned u = __builtin_bit_cast(unsigned, f);
    u += 0x7FFF + ((u >> 16) & 1);          // round-to-nearest-even
    return (u16)(u >> 16);
}
__device__ inline float bf2f(u16 h){
    unsigned u = ((unsigned)h) << 16;
    return __builtin_bit_cast(float, u);
}

// async global->LDS, 16B per lane; LDS dest = wave-uniform base + lane*16
__device__ inline void gl_lds16(const u16* g, u16* l){
    __builtin_amdgcn_global_load_lds(
        (const __attribute__((address_space(1))) void*)g,
        (__attribute__((address_space(3))) void*)l,
        16, 0, 0);
}

// ---------------------------------------------------------------------------
// bf16 MFMA GEMM:  C[M,N] = scale * A[M,K] @ BT[N,K]^T
// BMxBN tile, BK=64, 4 waves in 2x2 grid, per-wave (BM/2)x(BN/2) via
// FM x FN frags of 16x16x32 MFMA.
// T3 minimum 2-phase pipeline (m248-proven): double-buffered LDS;
//   per K-step: issue next tile's global_load_lds -> compute current
//   (ds_read+MFMA) -> s_waitcnt vmcnt(0) -> RAW s_barrier.
// Raw barrier avoids the compiler's vmcnt(0)-drain-at-__syncthreads, so the
// prefetch stays in flight UNDER the compute (the round-6 flaw).
// OUT_BF16: bf16 output. MASK: fp32 mask multiply in epilogue (q path only).
// CSKIP: skip tiles fully above causal diagonal. CK: causal K-extent.
// QKF: fused q/k projection — blockIdx.y = path*(128/BN)+nt.
// ---------------------------------------------------------------------------
template<int BM, int BN, int OUT_BF16, int MASK, int CSKIP, int CK, int QKF>
__launch_bounds__(256)
__global__ void gemm_bt(const u16* __restrict__ Ag, const u16* __restrict__ Bg,
                        const u16* __restrict__ Bg2,
                        void* __restrict__ Cg, void* __restrict__ Cg2,
                        const float* __restrict__ maskp,
                        int K, int lda, int ldb, int ldc,
                        long sA, long sB, long sC, float scale)
{
    constexpr int FM = BM / 32, FN = BN / 32;
    __shared__ u16 As[2][BM * 64];
    __shared__ u16 Bs[2][BN * 64];
    const int mt = blockIdx.x;
    int nt, path = 0;
    if (QKF) { constexpr int NT = C_DIM / BN; path = blockIdx.y / NT; nt = blockIdx.y % NT; }
    else nt = blockIdx.y;
    if (CSKIP && nt * BN >= (mt + 1) * BM) return;   // fully above diagonal
    const u16* Aa = Ag + (long)blockIdx.z * sA;
    const u16* Bb = ((QKF && path) ? Bg2 : Bg) + (long)blockIdx.z * sB;
    const int tid = threadIdx.x, lane = tid & 63, wave = tid >> 6;
    const int wr = wave >> 1, wc = wave & 1;
    const int mbase = mt * BM, nbase = nt * BN;
    int Keff = K;
    if (CK) { int ke = (mt + 1) * BM; Keff = ke < K ? ke : K; }
    const int nkt = Keff >> 6;

    f32x4 acc[FM][FN];
    #pragma unroll
    for (int m = 0; m < FM; ++m)
        #pragma unroll
        for (int n = 0; n < FN; ++n) acc[m][n] = (f32x4){0.f,0.f,0.f,0.f};

    // staging lane geometry: each wave stages 8 rows x 128B per shot;
    // lane covers 16B at XOR-swizzled col slot
    const int sr  = lane >> 3;                 // row within wave-chunk (0..7)
    const int sc8 = (lane & 7) ^ sr;           // swizzled 8-elem col slot

    auto STAGE = [&](int buf, int kt) {
        const int k0 = kt * 64;
        #pragma unroll
        for (int s = 0; s < BM / 32; ++s) {
            const int row = s * 32 + wave * 8 + sr;
            gl_lds16(Aa + (size_t)(mbase + row) * lda + k0 + sc8 * 8,
                     &As[buf][s * 2048 + wave * 512]);
        }
        #pragma unroll
        for (int s = 0; s < BN / 32; ++s) {
            const int row = s * 32 + wave * 8 + sr;
            gl_lds16(Bb + (size_t)(nbase + row) * ldb + k0 + sc8 * 8,
                     &Bs[buf][s * 2048 + wave * 512]);
        }
    };

    // prologue: stage tile 0, wait, raw barrier
    STAGE(0, 0);
    asm volatile("s_waitcnt vmcnt(0)" ::: "memory");
    __builtin_amdgcn_s_barrier();

    int cur = 0;
    for (int kt = 0; kt < nkt; ++kt) {
        const bool more = (kt + 1 < nkt);
        if (more) STAGE(cur ^ 1, kt + 1);   // issue next-tile loads (in flight
                                            // across the whole compute below)
        const u16* Ap = As[cur];
        const u16* Bp = Bs[cur];
        #pragma unroll
        for (int ks = 0; ks < 2; ++ks) {
            s16x8 af[FM], bfr[FN];
            const int k8 = ks * 4 + (lane >> 4);
            #pragma unroll
            for (int m = 0; m < FM; ++m) {
                const int row = wr * (BM / 2) + m * 16 + (lane & 15);
                af[m] = *(const s16x8*)&Ap[row * 64 + ((k8 ^ (row & 7)) << 3)];
            }
            #pragma unroll
            for (int n = 0; n < FN; ++n) {
                const int row = wc * (BN / 2) + n * 16 + (lane & 15);
                bfr[n] = *(const s16x8*)&Bp[row * 64 + ((k8 ^ (row & 7)) << 3)];
            }
            #pragma unroll
            for (int m = 0; m < FM; ++m)
                #pragma unroll
                for (int n = 0; n < FN; ++n)
                    acc[m][n] = __builtin_amdgcn_mfma_f32_16x16x32_bf16(af[m], bfr[n], acc[m][n], 0, 0, 0);
        }
        if (more) {
            // retire next-tile loads (mostly landed under the MFMA above),
            // then raw barrier: after it, all waves' loads are visible and
            // all waves are done reading buf cur.
            asm volatile("s_waitcnt vmcnt(0)" ::: "memory");
            __builtin_amdgcn_s_barrier();
            cur ^= 1;
        }
    }

    // epilogue: C/D layout col=lane&15, row=(lane>>4)*4+r (m89-verified)
    const bool kpath = QKF && path;
    void* Cout = kpath ? Cg2 : Cg;
    const int lr = (lane >> 4) * 4, lc = lane & 15;
    #pragma unroll
    for (int m = 0; m < FM; ++m) {
        #pragma unroll
        for (int n = 0; n < FN; ++n) {
            const int gr = mbase + wr * (BM / 2) + m * 16 + lr;
            const int gc = nbase + wc * (BN / 2) + n * 16 + lc;
            #pragma unroll
            for (int r = 0; r < 4; ++r) {
                float f = acc[m][n][r] * scale;
                const size_t off = (size_t)(gr + r) * ldc + gc;
                if (MASK) { if (!kpath) f *= maskp[(long)blockIdx.z * sC + off]; }
                if (OUT_BF16) ((u16*)Cout + (long)blockIdx.z * sC)[off] = f2bf(f);
                else          ((float*)Cout + (long)blockIdx.z * sC)[off] = f;
            }
        }
    }
}

// ---------------------------------------------------------------------------
// Row softmax over causal prefix, in place on bf16 scores (vectorized).
// Masked lanes fold to exp->0, which also zero-fills (q, 128-boundary).
// ---------------------------------------------------------------------------
__launch_bounds__(256)
__global__ void softmax_rows(u16* __restrict__ sc)
{
    __shared__ float v[SEQ];
    __shared__ float red[8];
    const int bq = blockIdx.x;
    const int q  = bq & (SEQ - 1);
    u16* row = sc + (size_t)bq * SEQ;
    const int tid = threadIdx.x;
    const int nk = q + 1;
    const int bound = ((q >> 7) + 1) << 7;   // next multiple of 128
    const int nv = bound >> 3;               // u16x8 chunks

    float lmax = -1e30f;
    for (int ci = tid; ci < nv; ci += 256) {
        const int base = ci * 8;
        u16x8 vv = *(const u16x8*)&row[base];
        #pragma unroll
        for (int j = 0; j < 8; ++j) {
            float f = (base + j < nk) ? bf2f(vv[j]) : -1e30f;
            v[base + j] = f;
            lmax = fmaxf(lmax, f);
        }
    }
    for (int off = 32; off; off >>= 1) lmax = fmaxf(lmax, __shfl_xor(lmax, off));
    if ((tid & 63) == 0) red[tid >> 6] = lmax;
    __syncthreads();
    const float m = fmaxf(fmaxf(red[0], red[1]), fmaxf(red[2], red[3]));

    float ls = 0.f;
    for (int ci = tid; ci < nv; ci += 256) {
        const int base = ci * 8;
        #pragma unroll
        for (int j = 0; j < 8; ++j) {
            float e = __expf(v[base + j] - m);   // masked: exp(-1e30-m)=0
            v[base + j] = e;
            ls += e;
        }
    }
    for (int off = 32; off; off >>= 1) ls += __shfl_xor(ls, off);
    if ((tid & 63) == 0) red[4 + (tid >> 6)] = ls;
    __syncthreads();
    const float inv = 1.f / (red[4] + red[5] + red[6] + red[7]);

    for (int ci = tid; ci < nv; ci += 256) {
        const int base = ci * 8;
        u16x8 o;
        #pragma unroll
        for (int j = 0; j < 8; ++j) o[j] = f2bf(v[base + j] * inv);
        *(u16x8*)&row[base] = o;
    }
}

// ---------------------------------------------------------------------------
// x prep: read x once; write xb (bf16 row-major) and xbT (bf16 [b][D][S])
// ---------------------------------------------------------------------------
__launch_bounds__(256)
__global__ void xprep(const float* __restrict__ x, u16* __restrict__ xb,
                      u16* __restrict__ xbT)
{
    __shared__ float t[32][33];
    const int b = blockIdx.z;
    const float* xp = x + (long)b * SEQ * D_MODEL;
    const int c0 = blockIdx.x * 32, r0 = blockIdx.y * 32;
    const int tx = threadIdx.x & 31, ty = threadIdx.x >> 5;   // ty 0..7
    #pragma unroll
    for (int i = 0; i < 32; i += 8) {
        const float f = xp[(size_t)(r0 + ty + i) * D_MODEL + c0 + tx];
        t[ty + i][tx] = f;
        xb[((long)b * SEQ + r0 + ty + i) * D_MODEL + c0 + tx] = f2bf(f);
    }
    __syncthreads();
    #pragma unroll
    for (int i = 0; i < 32; i += 8)
        xbT[((long)b * D_MODEL + c0 + ty + i) * SEQ + r0 + tx] = f2bf(t[tx][ty + i]);
}

// ---------------------------------------------------------------------------
// fp32 -> bf16 transpose (32x32 LDS tiles): out[c][r] = in[r][c]
// ---------------------------------------------------------------------------
__launch_bounds__(256)
__global__ void transpose_cvt(const float* __restrict__ in, u16* __restrict__ out,
                              int R, int Cc)
{
    __shared__ float t[32][33];
    const int c0 = blockIdx.x * 32, r0 = blockIdx.y * 32;
    const int tx = threadIdx.x & 31, ty = threadIdx.x >> 5;
    #pragma unroll
    for (int i = 0; i < 32; i += 8) t[ty + i][tx] = in[(size_t)(r0 + ty + i) * Cc + c0 + tx];
    __syncthreads();
    #pragma unroll
    for (int i = 0; i < 32; i += 8) out[(size_t)(c0 + ty + i) * R + r0 + tx] = f2bf(t[tx][ty + i]);
}

// fp32 -> bf16 straight convert (vectorized), n4 = n/4
__launch_bounds__(256)
__global__ void convert_cvt(const float* __restrict__ in, u16* __restrict__ out, int n4)
{
    for (int i = blockIdx.x * 256 + threadIdx.x; i < n4; i += gridDim.x * 256) {
        float4 f = reinterpret_cast<const float4*>(in)[i];
        u16x4 o = { f2bf(f.x), f2bf(f.y), f2bf(f.z), f2bf(f.w) };
        reinterpret_cast<u16x4*>(out)[i] = o;
    }
}

// ---------------------------------------------------------------------------
extern "C" void kernel_launch(void* const* d_in, const int* in_sizes, int n_in,
                              void* d_out, int out_size, void* d_ws, size_t ws_size,
                              hipStream_t stream)
{
    const float* x    = (const float*)d_in[0];
    const float* A    = (const float*)d_in[1];
    const float* Bm   = (const float*)d_in[2];
    const float* ov   = (const float*)d_in[3];
    const float* mask = (const float*)d_in[4];

    // workspace layout (bf16): total ~86.5 MiB
    char* w = (char*)d_ws;
    u16* xb  = (u16*)w; w += (size_t)BS_ROWS * D_MODEL * 2;   // x row-major
    u16* xbT = (u16*)w; w += (size_t)BS_ROWS * D_MODEL * 2;   // x^T per batch [D][S]
    u16* AbT = (u16*)w; w += (size_t)C_DIM * D_MODEL * 2;     // A^T [C][D]
    u16* Bmb = (u16*)w; w += (size_t)C_DIM * D_MODEL * 2;     // Bmat [C][D]
    u16* ovT = (u16*)w; w += (size_t)D_MODEL * D_MODEL * 2;   // ov^T [D][D]
    u16* qm  = (u16*)w; w += (size_t)BS_ROWS * C_DIM * 2;     // masked q
    u16* kk  = (u16*)w; w += (size_t)BS_ROWS * C_DIM * 2;     // k
    u16* sc  = (u16*)w; w += (size_t)BATCH * SEQ * SEQ * 2;   // scores -> P (in place)
    u16* zb  = (u16*)w; w += (size_t)BS_ROWS * D_MODEL * 2;   // z

    // prep: x (read once -> xb + xbT), Bmat convert, ov/A transposes
    xprep<<<dim3(D_MODEL/32, SEQ/32, BATCH), 256, 0, stream>>>(x, xb, xbT);
    convert_cvt<<<128, 256, 0, stream>>>(Bm, Bmb, C_DIM * D_MODEL / 4);
    transpose_cvt<<<dim3(D_MODEL/32, D_MODEL/32, 1), 256, 0, stream>>>(ov, ovT, D_MODEL, D_MODEL);
    transpose_cvt<<<dim3(C_DIM/32, D_MODEL/32, 1), 256, 0, stream>>>(A, AbT, D_MODEL, C_DIM);

    // fused q & k projection: 64x64 tiles, y = path*2 + nt -> 512 blocks
    gemm_bt<64,64,1,1,0,0,1><<<dim3(BS_ROWS/64, 4, 1), 256, 0, stream>>>(
        xb, AbT, Bmb, qm, kk, mask,
        D_MODEL, D_MODEL, D_MODEL, C_DIM, 0, 0, 0, 1.0f);

    // scores = qm @ kk^T / D  (128x128 tiles, causal lower tiles only)
    gemm_bt<128,128,1,0,1,0,0><<<dim3(SEQ/128, SEQ/128, BATCH), 256, 0, stream>>>(
        qm, kk, nullptr, sc, nullptr, nullptr, C_DIM, C_DIM, C_DIM, SEQ,
        (long)SEQ * C_DIM, (long)SEQ * C_DIM, (long)SEQ * SEQ, 1.0f / D_MODEL);

    softmax_rows<<<BS_ROWS, 256, 0, stream>>>(sc);

    // z = P @ x  (128x128 tiles, causal K-extent) -> 512 blocks
    gemm_bt<128,128,1,0,0,1,0><<<dim3(SEQ/128, D_MODEL/128, BATCH), 256, 0, stream>>>(
        sc, xbT, nullptr, zb, nullptr, nullptr, SEQ, SEQ, SEQ, D_MODEL,
        (long)SEQ * SEQ, (long)D_MODEL * SEQ, (long)SEQ * D_MODEL, 1.0f);

    // out = z @ ov  (128x128 tiles) -> 512 blocks, fp32 out
    gemm_bt<128,128,0,0,0,0,0><<<dim3(BS_ROWS/128, D_MODEL/128, 1), 256, 0, stream>>>(
        zb, ovT, nullptr, d_out, nullptr, nullptr, D_MODEL, D_MODEL, D_MODEL, D_MODEL,
        0, 0, 0, 1.0f);
}